// Round 4
// baseline (372.525 us; speedup 1.0000x reference)
//
#include <hip/hip_runtime.h>

typedef unsigned short u16;
typedef _Float16 f16;
typedef _Float16 f16x4 __attribute__((ext_vector_type(4)));
typedef _Float16 f16x8 __attribute__((ext_vector_type(8)));
typedef float    f32x4 __attribute__((ext_vector_type(4)));

#define BATCH 8
#define SEQ   4096
#define EMB   512
#define NCOL  512   // H*d = 8*64

// ---------------------------------------------------------------------------
// Prepass: 5 planes, transpose W (f32 [k=512][n=512]) into f16 [n][k]:
//   z=0 WQ-hi, 1 WQ-lo4 = (x-hi)*16, 2 WK-hi, 3 WK-lo4, 4 WV.
// Recombine inside the MFMA accumulator:  w ~= wh + wl4*2^-4.
__global__ __launch_bounds__(256) void prep_w(
    const float* __restrict__ Wq, const float* __restrict__ Wk,
    const float* __restrict__ Wv, u16* __restrict__ out)
{
  __shared__ u16 tile[64][65];
  const int z = blockIdx.z;
  const float* in = (z < 2) ? Wq : (z < 4) ? Wk : Wv;
  const bool lo = (z == 1 || z == 3);
  u16* o = out + (size_t)z * EMB * NCOL;
  const int r0 = blockIdx.y * 64, c0 = blockIdx.x * 64;
  const int tx = threadIdx.x, ty = threadIdx.y;
#pragma unroll
  for (int i = 0; i < 16; ++i) {
    const int r = ty * 16 + i;
    const float x = in[(size_t)(r0 + r) * NCOL + (c0 + tx)];
    const f16 h = (f16)x;
    const f16 v = lo ? (f16)((x - (float)h) * 16.0f) : h;
    tile[r][tx] = __builtin_bit_cast(u16, v);
  }
  __syncthreads();
#pragma unroll
  for (int i = 0; i < 16; ++i) {
    const int rr = ty * 16 + i;
    o[(size_t)(c0 + rr) * EMB + (r0 + tx)] = tile[tx][rr];
  }
}

// ---------------------------------------------------------------------------
// Fused v5: occupancy fix. Wave tile 64 rows x 16 cols (rt=4, ct=1) ->
//   acc = 48 VGPR; launch_bounds(512,4) pins 128 regs -> 2 blocks/CU.
//   Block: 512 thr (8 waves), tile = 64 rows x 128 cols; grid.y = 4.
//   W B-frags global->reg (L2-resident); X staged to LDS as f16-split
//   planes (qh, ql4, kh, kl4, v) with XOR-swizzled 16B units.
//   q = qh*wh + (qh*2^-4)*wl4 + ql4*(wh*2^-4) into ONE f32 acc.
//   Softmax over d=64 spans the 4 waves of a head via LDS (m, sum) exchange.
#define PLANE 2048              // f16 per plane: 64 rows x 32
#define BUFSZ (5*PLANE)         // 10240 f16 = 20 KB

__global__ __launch_bounds__(512, 4) void fused_attn(
    const float* __restrict__ Xq, const float* __restrict__ Xk,
    const float* __restrict__ Xv,
    const int* __restrict__ Qlen, const int* __restrict__ Vlen,
    const u16* __restrict__ Wt,   // 5 planes of [512 n][512 k] f16
    float* __restrict__ out)
{
  const int b  = blockIdx.z;
  const int s0 = blockIdx.x * 64;
  const int c0 = blockIdx.y * 128;
  const int qlen = Qlen[b];
  const int t = threadIdx.x;

  if (s0 >= qlen) {           // fully masked tile: write zeros (64 x 128)
    const f32x4 z4 = {0.f, 0.f, 0.f, 0.f};
#pragma unroll
    for (int it = 0; it < 4; ++it) {
      const int f4  = it * 512 + t;
      const int row = f4 >> 5;
      const int col = (f4 & 31) * 4;
      *(f32x4*)(out + (size_t)(b * SEQ + s0 + row) * NCOL + c0 + col) = z4;
    }
    return;
  }
  const int vlen = Vlen[b];
  const int vl = (vlen == 0) ? 64 : vlen;  // uniform -1e12 shift cancels in softmax

  __shared__ f16 smem[2 * BUFSZ] __attribute__((aligned(16)));   // 40 KB

  const int w    = t >> 6;      // 0..7 = col-slice index (16 cols each)
  const int lane = t & 63;
  const int quad = lane >> 4;
  const int l15  = lane & 15;

  // staging lane mapping: 512 lanes cover [64 rows][32 k], 4 f32 each
  const int    srow = t >> 3;            // 0..63
  const int    sj   = t & 7;             // 0..7 (4-float chunk)
  const size_t xg   = (size_t)(b * SEQ + s0 + srow) * EMB + sj * 4;
  const int    swo  = srow * 32 + (((sj >> 1) ^ ((srow >> 1) & 3)) * 8) + (sj & 1) * 4;

  // W global bases (per-lane): col = c0 + w*16 + l15, k = kk + quad*8
  const size_t wb = (size_t)(c0 + w * 16 + l15) * EMB + quad * 8;
  const u16* Wqh_g = Wt                + wb;
  const u16* Wql_g = Wt + 1 * EMB*NCOL + wb;
  const u16* Wkh_g = Wt + 2 * EMB*NCOL + wb;
  const u16* Wkl_g = Wt + 3 * EMB*NCOL + wb;
  const u16* Wv_g  = Wt + 4 * EMB*NCOL + wb;

  // A-frag LDS base (f16 elems), matches staging swizzle:
  const int swz = (l15 >> 1) & 3;
  const int ao  = l15 * 32 + ((quad ^ swz) * 8);

  f32x4 accQ[4], accK[4], accV[4];
#pragma unroll
  for (int rt = 0; rt < 4; ++rt) {
    const f32x4 z = {0.f, 0.f, 0.f, 0.f};
    accQ[rt] = z; accK[rt] = z; accV[rt] = z;
  }

  f32x4 rq, rk, rv;   // single in-flight staging slot

#define LOADX(TT) do { \
    rq = *(const f32x4*)(Xq + xg + (TT) * 32); \
    rk = *(const f32x4*)(Xk + xg + (TT) * 32); \
    rv = *(const f32x4*)(Xv + xg + (TT) * 32); \
  } while (0)

#define STAGE(BOFS) do { \
    f16* p_ = smem + (BOFS); \
    f16x4 qh_, ql_, kh_, kl_, vh_; \
    _Pragma("unroll") \
    for (int j = 0; j < 4; ++j) { \
      const float xq_ = rq[j]; const f16 qhh_ = (f16)xq_; \
      qh_[j] = qhh_; ql_[j] = (f16)((xq_ - (float)qhh_) * 16.0f); \
      const float xk_ = rk[j]; const f16 khh_ = (f16)xk_; \
      kh_[j] = khh_; kl_[j] = (f16)((xk_ - (float)khh_) * 16.0f); \
      vh_[j] = (f16)rv[j]; \
    } \
    *(f16x4*)(p_ + 0 * PLANE + swo) = qh_; \
    *(f16x4*)(p_ + 1 * PLANE + swo) = ql_; \
    *(f16x4*)(p_ + 2 * PLANE + swo) = kh_; \
    *(f16x4*)(p_ + 3 * PLANE + swo) = kl_; \
    *(f16x4*)(p_ + 4 * PLANE + swo) = vh_; \
  } while (0)

#define COMPUTE(BOFS, KK) do { \
    const f16* p_ = smem + (BOFS); \
    const int kk_ = (KK); \
    /* ---- Q phase ---- */ \
    { \
      const f16x8 bh_ = *(const f16x8*)(Wqh_g + kk_); \
      const f16x8 bl_ = *(const f16x8*)(Wql_g + kk_); \
      f16x8 b4_; \
      _Pragma("unroll") \
      for (int jj = 0; jj < 8; ++jj) b4_[jj] = bh_[jj] * (f16)0.0625f; \
      _Pragma("unroll") \
      for (int rt = 0; rt < 4; ++rt) { \
        const int ao_ = ao + rt * 512; \
        const f16x8 ah_ = *(const f16x8*)(p_ + 0 * PLANE + ao_); \
        const f16x8 al_ = *(const f16x8*)(p_ + 1 * PLANE + ao_); \
        f16x8 a4_; \
        _Pragma("unroll") \
        for (int jj = 0; jj < 8; ++jj) a4_[jj] = ah_[jj] * (f16)0.0625f; \
        accQ[rt] = __builtin_amdgcn_mfma_f32_16x16x32_f16(ah_, bh_, accQ[rt], 0, 0, 0); \
        accQ[rt] = __builtin_amdgcn_mfma_f32_16x16x32_f16(a4_, bl_, accQ[rt], 0, 0, 0); \
        accQ[rt] = __builtin_amdgcn_mfma_f32_16x16x32_f16(al_, b4_, accQ[rt], 0, 0, 0); \
      } \
    } \
    /* ---- K phase ---- */ \
    { \
      const f16x8 bh_ = *(const f16x8*)(Wkh_g + kk_); \
      const f16x8 bl_ = *(const f16x8*)(Wkl_g + kk_); \
      f16x8 b4_; \
      _Pragma("unroll") \
      for (int jj = 0; jj < 8; ++jj) b4_[jj] = bh_[jj] * (f16)0.0625f; \
      _Pragma("unroll") \
      for (int rt = 0; rt < 4; ++rt) { \
        const int ao_ = ao + rt * 512; \
        const f16x8 ah_ = *(const f16x8*)(p_ + 2 * PLANE + ao_); \
        const f16x8 al_ = *(const f16x8*)(p_ + 3 * PLANE + ao_); \
        f16x8 a4_; \
        _Pragma("unroll") \
        for (int jj = 0; jj < 8; ++jj) a4_[jj] = ah_[jj] * (f16)0.0625f; \
        accK[rt] = __builtin_amdgcn_mfma_f32_16x16x32_f16(ah_, bh_, accK[rt], 0, 0, 0); \
        accK[rt] = __builtin_amdgcn_mfma_f32_16x16x32_f16(a4_, bl_, accK[rt], 0, 0, 0); \
        accK[rt] = __builtin_amdgcn_mfma_f32_16x16x32_f16(al_, b4_, accK[rt], 0, 0, 0); \
      } \
    } \
    /* ---- V phase ---- */ \
    { \
      const f16x8 bv_ = *(const f16x8*)(Wv_g + kk_); \
      _Pragma("unroll") \
      for (int rt = 0; rt < 4; ++rt) { \
        const f16x8 av_ = *(const f16x8*)(p_ + 4 * PLANE + ao + rt * 512); \
        accV[rt] = __builtin_amdgcn_mfma_f32_16x16x32_f16(av_, bv_, accV[rt], 0, 0, 0); \
      } \
    } \
  } while (0)

  // Prologue: stage data 0 into buf0.
  LOADX(0);
  STAGE(0);
  __syncthreads();

  // 16 K-tiles of 32; one barrier per step; unroll x2 for buffer toggle.
#pragma unroll 1
  for (int tt = 0; tt < 16; tt += 2) {
    // even step: compute buf0, stage data tt+1 into buf1
    LOADX(tt + 1);
    COMPUTE(0, tt * 32);
    STAGE(BUFSZ);
    __syncthreads();
    // odd step: compute buf1, stage data tt+2 into buf0
    if (tt < 14) LOADX(tt + 2);
    COMPUTE(BUFSZ, (tt + 1) * 32);
    if (tt < 14) STAGE(0);
    __syncthreads();
  }

#undef LOADX
#undef STAGE
#undef COMPUTE

  // -------------------------------------------------------------------------
  // Epilogue. Wave covers cols [w*16, w*16+16) within the block's 128-col
  // slab; head d = (w&3)*16 + l15; softmax over d=64 combines the 4 waves
  // with the same (w>>2) via an LDS (max, sum) exchange.
  const float scale = 0.125f;     // 1/sqrt(64)
  float* smf = (float*)smem;      // [8 waves][64 rows][2] = 4 KB (buf0 region)

  float eA[4][4];                 // exp(a - m_local), [rt][r]

#pragma unroll
  for (int rt = 0; rt < 4; ++rt) {
#pragma unroll
    for (int r = 0; r < 4; ++r) {
      const float a = accQ[rt][r] * accK[rt][r] * scale;
      const bool msk = ((w & 3) * 16 + l15) < vl;
      float mx = msk ? a : -3.0e38f;
#pragma unroll
      for (int off = 1; off < 16; off <<= 1) mx = fmaxf(mx, __shfl_xor(mx, off));
      const float e = msk ? __expf(a - mx) : 0.0f;
      eA[rt][r] = e;
      float sum = e;
#pragma unroll
      for (int off = 1; off < 16; off <<= 1) sum += __shfl_xor(sum, off);
      const int row = rt * 16 + quad * 4 + r;
      if (l15 == 0) {
        smf[(w * 64 + row) * 2 + 0] = mx;
        smf[(w * 64 + row) * 2 + 1] = sum;
      }
    }
  }
  __syncthreads();

  const int wbase = w & 4;        // first wave of this head's 4-wave group
#pragma unroll
  for (int rt = 0; rt < 4; ++rt) {
#pragma unroll
    for (int r = 0; r < 4; ++r) {
      const int row = rt * 16 + quad * 4 + r;
      const int s   = s0 + row;
      float pm[4], ps[4];
      float M = -3.0e38f;
#pragma unroll
      for (int j = 0; j < 4; ++j) {
        pm[j] = smf[((wbase + j) * 64 + row) * 2 + 0];
        ps[j] = smf[((wbase + j) * 64 + row) * 2 + 1];
        M = fmaxf(M, pm[j]);
      }
      float S = 0.f;
#pragma unroll
      for (int j = 0; j < 4; ++j) S += ps[j] * __expf(pm[j] - M);
      const float qm = (s < qlen) ? 1.0f : 0.0f;
      const float f  = __expf(pm[w & 3] - M) * qm / S;
      const size_t ob = (size_t)(b * SEQ + s) * NCOL + c0 + w * 16 + l15;
      out[ob] = eA[rt][r] * f * accV[rt][r];
    }
  }
}

// ---------------------------------------------------------------------------
extern "C" void kernel_launch(void* const* d_in, const int* in_sizes, int n_in,
                              void* d_out, int out_size, void* d_ws, size_t ws_size,
                              hipStream_t stream) {
  const float* Xq   = (const float*)d_in[0];
  const float* Xk   = (const float*)d_in[1];
  const float* Xv   = (const float*)d_in[2];
  const int*   Qlen = (const int*)d_in[3];
  const int*   Vlen = (const int*)d_in[4];
  const float* Wq   = (const float*)d_in[5];
  const float* Wk   = (const float*)d_in[6];
  const float* Wv   = (const float*)d_in[7];
  u16*   Wt  = (u16*)d_ws;              // 5 * 512*512 * 2B = 2.5 MB
  float* out = (float*)d_out;

  dim3 pg(8, 8, 5), pb(64, 4, 1);
  prep_w<<<pg, pb, 0, stream>>>(Wq, Wk, Wv, Wt);

  dim3 g(SEQ / 64, NCOL / 128, BATCH), blk(512, 1, 1);
  fused_attn<<<g, blk, 0, stream>>>(Xq, Xk, Xv, Qlen, Vlen, Wt, out);
}

// Round 5
// 328.077 us; speedup vs baseline: 1.1355x; 1.1355x over previous
//
#include <hip/hip_runtime.h>

typedef unsigned short u16;
typedef unsigned int   u32;
typedef _Float16 f16;
typedef _Float16 f16x4 __attribute__((ext_vector_type(4)));
typedef _Float16 f16x8 __attribute__((ext_vector_type(8)));
typedef float    f32x4 __attribute__((ext_vector_type(4)));

#define BATCH 8
#define SEQ   4096
#define EMB   512
#define NCOL  512   // H*d = 8*64
#define NTILES 2048 // 64 s-tiles x 4 col-tiles x 8 batches

// ---------------------------------------------------------------------------
// Prepass: 5 planes, transpose W (f32 [k=512][n=512]) into f16 [n][k]:
//   z=0 WQ-hi, 1 WQ-lo = RAW residual (x - hi), 2 WK-hi, 3 WK-lo, 4 WV.
// Recombine inside the MFMA accumulator: w ~= wh + wl (no scaling needed).
__global__ __launch_bounds__(256) void prep_w(
    const float* __restrict__ Wq, const float* __restrict__ Wk,
    const float* __restrict__ Wv, u16* __restrict__ out)
{
  __shared__ u16 tile[64][65];
  const int z = blockIdx.z;
  const float* in = (z < 2) ? Wq : (z < 4) ? Wk : Wv;
  const bool lo = (z == 1 || z == 3);
  u16* o = out + (size_t)z * EMB * NCOL;
  const int r0 = blockIdx.y * 64, c0 = blockIdx.x * 64;
  const int tx = threadIdx.x, ty = threadIdx.y;
#pragma unroll
  for (int i = 0; i < 16; ++i) {
    const int r = ty * 16 + i;
    const float x = in[(size_t)(r0 + r) * NCOL + (c0 + tx)];
    const f16 h = (f16)x;
    const f16 v = lo ? (f16)(x - (float)h) : h;
    tile[r][tx] = __builtin_bit_cast(u16, v);
  }
  __syncthreads();
#pragma unroll
  for (int i = 0; i < 16; ++i) {
    const int rr = ty * 16 + i;
    o[(size_t)(c0 + rr) * EMB + (r0 + tx)] = tile[tx][rr];
  }
}

__global__ void reset_cnt(u32* cnt) { if (threadIdx.x == 0) *cnt = 0; }

// ---------------------------------------------------------------------------
// Fused v6: persistent blocks + dynamic tile queue + raw-residual split.
//   1024 blocks (4/CU resident, LDS 40 KB, VGPR target <=64), each grabs
//   tiles (64 rows x 128 cols) from a global counter until NTILES consumed.
//   Wave w owns 64 rows x 16 cols (rt=4, ct=1); W B-frags global->reg.
//   X staged to LDS as f16 planes (qh, ql=raw-res, kh, kl, v), XOR-swizzled.
//   q = qh*wh + qh*wl + ql*wh into ONE f32 acc -- zero VALU rescale.
//   Softmax over d=64 spans the 4 waves of a head via LDS (m, sum) exchange.
#define PLANE 2048              // f16 per plane: 64 rows x 32
#define BUFSZ (5*PLANE)         // 10240 f16 = 20 KB

__global__ __launch_bounds__(512, 4) void fused_attn(
    const float* __restrict__ Xq, const float* __restrict__ Xk,
    const float* __restrict__ Xv,
    const int* __restrict__ Qlen, const int* __restrict__ Vlen,
    const u16* __restrict__ Wt,   // 5 planes of [512 n][512 k] f16
    float* __restrict__ out, u32* cnt, const int dyn)
{
  const int t = threadIdx.x;

  __shared__ f16 smem[2 * BUFSZ] __attribute__((aligned(16)));   // 40960 B
  // tile-broadcast slot aliased into the LAST 4 bytes of buf1 (no extra LDS)
  int* slot = (int*)((char*)smem + 2 * BUFSZ * 2 - 4);

  const int w    = t >> 6;      // 0..7 = col-slice index (16 cols each)
  const int lane = t & 63;
  const int quad = lane >> 4;
  const int l15  = lane & 15;

  // staging lane mapping: 512 lanes cover [64 rows][32 k], 4 f32 each
  const int srow = t >> 3;               // 0..63
  const int sj   = t & 7;                // 0..7 (4-float chunk)
  const int sk4  = sj * 4;
  const int swo  = srow * 32 + (((sj >> 1) ^ ((srow >> 1) & 3)) * 8) + (sj & 1) * 4;

  // A-frag LDS base (f16 elems), matches staging swizzle:
  const int swz = (l15 >> 1) & 3;
  const int ao  = l15 * 32 + ((quad ^ swz) * 8);

  const float scale = 0.125f;   // 1/sqrt(64)
  int tile_static = (int)blockIdx.x;   // used only when !dyn

  for (;;) {
    // ---- grab next tile (thread 0), broadcast via LDS ----
    if (t == 0) {
      const int nt = dyn ? (int)atomicAdd(cnt, 1u) : tile_static;
      tile_static = NTILES;            // static mode: one tile then stop
      *slot = nt;
    }
    __syncthreads();                   // also fences prev epilogue smf reads
    const int tile = __builtin_amdgcn_readfirstlane(*slot);
    if (tile >= NTILES) break;

    const int s0 = (tile & 63) * 64;
    const int c0 = ((tile >> 6) & 3) * 128;
    const int b  = tile >> 8;
    const int qlen = Qlen[b];

    if (s0 >= qlen) {                  // fully masked tile: zeros (64 x 128)
      const f32x4 z4 = {0.f, 0.f, 0.f, 0.f};
#pragma unroll
      for (int it = 0; it < 4; ++it) {
        const int f4  = it * 512 + t;
        const int row = f4 >> 5;
        const int col = (f4 & 31) * 4;
        *(f32x4*)(out + (size_t)(b * SEQ + s0 + row) * NCOL + c0 + col) = z4;
      }
      continue;
    }
    const int vlen = Vlen[b];
    const int vl = (vlen == 0) ? 64 : vlen;  // uniform -1e12 shift cancels

    const size_t xg = (size_t)(b * SEQ + s0 + srow) * EMB + sk4;
    const size_t wb = (size_t)(c0 + w * 16 + l15) * EMB + quad * 8;
    const u16* Wqh_g = Wt                + wb;
    const u16* Wql_g = Wt + 1 * EMB*NCOL + wb;
    const u16* Wkh_g = Wt + 2 * EMB*NCOL + wb;
    const u16* Wkl_g = Wt + 3 * EMB*NCOL + wb;
    const u16* Wv_g  = Wt + 4 * EMB*NCOL + wb;

    f32x4 accQ[4], accK[4], accV[4];
#pragma unroll
    for (int rt = 0; rt < 4; ++rt) {
      const f32x4 z = {0.f, 0.f, 0.f, 0.f};
      accQ[rt] = z; accK[rt] = z; accV[rt] = z;
    }

    f32x4 rq, rk, rv;   // single in-flight staging slot

#define LOADX(TT) do { \
      rq = *(const f32x4*)(Xq + xg + (TT) * 32); \
      rk = *(const f32x4*)(Xk + xg + (TT) * 32); \
      rv = *(const f32x4*)(Xv + xg + (TT) * 32); \
    } while (0)

#define STAGE(BOFS) do { \
      f16* p_ = smem + (BOFS); \
      f16x4 qh_, ql_, kh_, kl_, vh_; \
      _Pragma("unroll") \
      for (int j = 0; j < 4; ++j) { \
        const float xq_ = rq[j]; const f16 qhh_ = (f16)xq_; \
        qh_[j] = qhh_; ql_[j] = (f16)(xq_ - (float)qhh_); \
        const float xk_ = rk[j]; const f16 khh_ = (f16)xk_; \
        kh_[j] = khh_; kl_[j] = (f16)(xk_ - (float)khh_); \
        vh_[j] = (f16)rv[j]; \
      } \
      *(f16x4*)(p_ + 0 * PLANE + swo) = qh_; \
      *(f16x4*)(p_ + 1 * PLANE + swo) = ql_; \
      *(f16x4*)(p_ + 2 * PLANE + swo) = kh_; \
      *(f16x4*)(p_ + 3 * PLANE + swo) = kl_; \
      *(f16x4*)(p_ + 4 * PLANE + swo) = vh_; \
    } while (0)

#define COMPUTE(BOFS, KK) do { \
      const f16* p_ = smem + (BOFS); \
      const f16x8 bqh_ = *(const f16x8*)(Wqh_g + (KK)); \
      const f16x8 bql_ = *(const f16x8*)(Wql_g + (KK)); \
      const f16x8 bkh_ = *(const f16x8*)(Wkh_g + (KK)); \
      const f16x8 bkl_ = *(const f16x8*)(Wkl_g + (KK)); \
      const f16x8 bv_  = *(const f16x8*)(Wv_g  + (KK)); \
      _Pragma("unroll") \
      for (int rt = 0; rt < 4; ++rt) { \
        const int ao_ = ao + rt * 512; \
        const f16x8 ah_ = *(const f16x8*)(p_ + 0 * PLANE + ao_); \
        const f16x8 al_ = *(const f16x8*)(p_ + 1 * PLANE + ao_); \
        accQ[rt] = __builtin_amdgcn_mfma_f32_16x16x32_f16(ah_, bqh_, accQ[rt], 0, 0, 0); \
        accQ[rt] = __builtin_amdgcn_mfma_f32_16x16x32_f16(ah_, bql_, accQ[rt], 0, 0, 0); \
        accQ[rt] = __builtin_amdgcn_mfma_f32_16x16x32_f16(al_, bqh_, accQ[rt], 0, 0, 0); \
      } \
      _Pragma("unroll") \
      for (int rt = 0; rt < 4; ++rt) { \
        const int ao_ = ao + rt * 512; \
        const f16x8 ah_ = *(const f16x8*)(p_ + 2 * PLANE + ao_); \
        const f16x8 al_ = *(const f16x8*)(p_ + 3 * PLANE + ao_); \
        accK[rt] = __builtin_amdgcn_mfma_f32_16x16x32_f16(ah_, bkh_, accK[rt], 0, 0, 0); \
        accK[rt] = __builtin_amdgcn_mfma_f32_16x16x32_f16(ah_, bkl_, accK[rt], 0, 0, 0); \
        accK[rt] = __builtin_amdgcn_mfma_f32_16x16x32_f16(al_, bkh_, accK[rt], 0, 0, 0); \
      } \
      _Pragma("unroll") \
      for (int rt = 0; rt < 4; ++rt) { \
        const f16x8 av_ = *(const f16x8*)(p_ + 4 * PLANE + ao + rt * 512); \
        accV[rt] = __builtin_amdgcn_mfma_f32_16x16x32_f16(av_, bv_, accV[rt], 0, 0, 0); \
      } \
    } while (0)

    // Prologue: stage data 0 into buf0.
    LOADX(0);
    STAGE(0);
    __syncthreads();

    // 16 K-tiles of 32; one barrier per step; unroll x2 for buffer toggle.
#pragma unroll 1
    for (int tt = 0; tt < 16; tt += 2) {
      LOADX(tt + 1);
      COMPUTE(0, tt * 32);
      STAGE(BUFSZ);
      __syncthreads();
      if (tt < 14) LOADX(tt + 2);
      COMPUTE(BUFSZ, (tt + 1) * 32);
      if (tt < 14) STAGE(0);
      __syncthreads();
    }

#undef LOADX
#undef STAGE
#undef COMPUTE

    // -----------------------------------------------------------------------
    // Epilogue. Wave covers cols [w*16, w*16+16); head = (c0 + w*16)/64;
    // softmax over d=64 combines the head's 4 waves via LDS (max, sum).
    float* smf = (float*)smem;    // [8 waves][64 rows][2] = 4 KB (buf0)
    float eA[4][4];               // exp(a - m_local), [rt][r]

#pragma unroll
    for (int rt = 0; rt < 4; ++rt) {
#pragma unroll
      for (int r = 0; r < 4; ++r) {
        const float a = accQ[rt][r] * accK[rt][r] * scale;
        const bool msk = ((w & 3) * 16 + l15) < vl;
        float mx = msk ? a : -3.0e38f;
#pragma unroll
        for (int off = 1; off < 16; off <<= 1) mx = fmaxf(mx, __shfl_xor(mx, off));
        const float e = msk ? __expf(a - mx) : 0.0f;
        eA[rt][r] = e;
        float sum = e;
#pragma unroll
        for (int off = 1; off < 16; off <<= 1) sum += __shfl_xor(sum, off);
        const int row = rt * 16 + quad * 4 + r;
        if (l15 == 0) {
          smf[(w * 64 + row) * 2 + 0] = mx;
          smf[(w * 64 + row) * 2 + 1] = sum;
        }
      }
    }
    __syncthreads();

    const int wbase = w & 4;      // first wave of this head's 4-wave group
#pragma unroll
    for (int rt = 0; rt < 4; ++rt) {
#pragma unroll
      for (int r = 0; r < 4; ++r) {
        const int row = rt * 16 + quad * 4 + r;
        const int s   = s0 + row;
        float pm[4], ps[4];
        float M = -3.0e38f;
#pragma unroll
        for (int j = 0; j < 4; ++j) {
          pm[j] = smf[((wbase + j) * 64 + row) * 2 + 0];
          ps[j] = smf[((wbase + j) * 64 + row) * 2 + 1];
          M = fmaxf(M, pm[j]);
        }
        float S = 0.f;
#pragma unroll
        for (int j = 0; j < 4; ++j) S += ps[j] * __expf(pm[j] - M);
        const float qm = (s < qlen) ? 1.0f : 0.0f;
        const float f  = __expf(pm[w & 3] - M) * qm / S;
        const size_t ob = (size_t)(b * SEQ + s) * NCOL + c0 + w * 16 + l15;
        out[ob] = eA[rt][r] * f * accV[rt][r];
      }
    }
    // loop back: top-of-loop barrier protects smf before next tile's STAGE
  }
}

// ---------------------------------------------------------------------------
extern "C" void kernel_launch(void* const* d_in, const int* in_sizes, int n_in,
                              void* d_out, int out_size, void* d_ws, size_t ws_size,
                              hipStream_t stream) {
  const float* Xq   = (const float*)d_in[0];
  const float* Xk   = (const float*)d_in[1];
  const float* Xv   = (const float*)d_in[2];
  const int*   Qlen = (const int*)d_in[3];
  const int*   Vlen = (const int*)d_in[4];
  const float* Wq   = (const float*)d_in[5];
  const float* Wk   = (const float*)d_in[6];
  const float* Wv   = (const float*)d_in[7];
  u16*   Wt  = (u16*)d_ws;              // 5 * 512*512 * 2B = 2.62 MB
  float* out = (float*)d_out;

  const size_t wt_bytes = (size_t)5 * EMB * NCOL * sizeof(u16);
  u32* cnt = (u32*)((char*)d_ws + wt_bytes);
  const int dyn = (ws_size >= wt_bytes + sizeof(u32)) ? 1 : 0;

  dim3 pg(8, 8, 5), pb(64, 4, 1);
  prep_w<<<pg, pb, 0, stream>>>(Wq, Wk, Wv, Wt);
  if (dyn) reset_cnt<<<1, 64, 0, stream>>>(cnt);

  dim3 g(dyn ? 1024 : NTILES, 1, 1), blk(512, 1, 1);
  fused_attn<<<g, blk, 0, stream>>>(Xq, Xk, Xv, Qlen, Vlen, Wt, out, cnt, dyn);
}

// Round 6
// 320.618 us; speedup vs baseline: 1.1619x; 1.0233x over previous
//
#include <hip/hip_runtime.h>

typedef unsigned short u16;
typedef unsigned int   u32;
typedef _Float16 f16;
typedef _Float16 f16x4 __attribute__((ext_vector_type(4)));
typedef _Float16 f16x8 __attribute__((ext_vector_type(8)));
typedef float    f32x4 __attribute__((ext_vector_type(4)));

#define BATCH 8
#define SEQ   4096
#define EMB   512
#define NCOL  512   // H*d = 8*64
#define NTILES 2048 // 64 s-tiles x 4 col-tiles x 8 batches

// ---------------------------------------------------------------------------
// Prepass: 5 planes, transpose W (f32 [k=512][n=512]) into f16 [n][k]:
//   z=0 WQ-hi, 1 WQ-lo = RAW residual (x - hi), 2 WK-hi, 3 WK-lo, 4 WV.
// Recombine inside the MFMA accumulator: w ~= wh + wl (no scaling needed).
__global__ __launch_bounds__(256) void prep_w(
    const float* __restrict__ Wq, const float* __restrict__ Wk,
    const float* __restrict__ Wv, u16* __restrict__ out)
{
  __shared__ u16 tile[64][65];
  const int z = blockIdx.z;
  const float* in = (z < 2) ? Wq : (z < 4) ? Wk : Wv;
  const bool lo = (z == 1 || z == 3);
  u16* o = out + (size_t)z * EMB * NCOL;
  const int r0 = blockIdx.y * 64, c0 = blockIdx.x * 64;
  const int tx = threadIdx.x, ty = threadIdx.y;
#pragma unroll
  for (int i = 0; i < 16; ++i) {
    const int r = ty * 16 + i;
    const float x = in[(size_t)(r0 + r) * NCOL + (c0 + tx)];
    const f16 h = (f16)x;
    const f16 v = lo ? (f16)(x - (float)h) : h;
    tile[r][tx] = __builtin_bit_cast(u16, v);
  }
  __syncthreads();
#pragma unroll
  for (int i = 0; i < 16; ++i) {
    const int rr = ty * 16 + i;
    o[(size_t)(c0 + rr) * EMB + (r0 + tx)] = tile[tx][rr];
  }
}

__global__ void reset_cnt(u32* cnt) { if (threadIdx.x == 0) *cnt = 0; }

// ---------------------------------------------------------------------------
// Fused v7 = v6 + V_len wave-skip + setprio.
//   1024 persistent blocks, dynamic tile queue; wave w owns 64 rows x 16 cols.
//   NEW: a wave whose 16 head-local cols are ALL >= vl produces exact zeros
//   (softmax e = 0 there) -> skips every COMPUTE (B-loads, ds_reads, MFMAs)
//   and writes (-inf, 0) sentinels into the softmax exchange. Wave-uniform
//   branch; removes ~37% of MFMA + A-LDS traffic in expectation.
#define PLANE 2048              // f16 per plane: 64 rows x 32
#define BUFSZ (5*PLANE)         // 10240 f16 = 20 KB

__global__ __launch_bounds__(512, 4) void fused_attn(
    const float* __restrict__ Xq, const float* __restrict__ Xk,
    const float* __restrict__ Xv,
    const int* __restrict__ Qlen, const int* __restrict__ Vlen,
    const u16* __restrict__ Wt,   // 5 planes of [512 n][512 k] f16
    float* __restrict__ out, u32* cnt, const int dyn)
{
  const int t = threadIdx.x;

  __shared__ f16 smem[2 * BUFSZ] __attribute__((aligned(16)));   // 40960 B
  // tile-broadcast slot aliased into the LAST 4 bytes of buf1 (no extra LDS)
  int* slot = (int*)((char*)smem + 2 * BUFSZ * 2 - 4);

  const int w    = t >> 6;      // 0..7 = col-slice index (16 cols each)
  const int lane = t & 63;
  const int quad = lane >> 4;
  const int l15  = lane & 15;

  // staging lane mapping: 512 lanes cover [64 rows][32 k], 4 f32 each
  const int srow = t >> 3;               // 0..63
  const int sj   = t & 7;                // 0..7 (4-float chunk)
  const int sk4  = sj * 4;
  const int swo  = srow * 32 + (((sj >> 1) ^ ((srow >> 1) & 3)) * 8) + (sj & 1) * 4;

  // A-frag LDS base (f16 elems), matches staging swizzle:
  const int swz = (l15 >> 1) & 3;
  const int ao  = l15 * 32 + ((quad ^ swz) * 8);

  const float scale = 0.125f;   // 1/sqrt(64)
  int tile_static = (int)blockIdx.x;   // used only when !dyn

  for (;;) {
    // ---- grab next tile (thread 0), broadcast via LDS ----
    if (t == 0) {
      const int nt = dyn ? (int)atomicAdd(cnt, 1u) : tile_static;
      tile_static = NTILES;            // static mode: one tile then stop
      *slot = nt;
    }
    __syncthreads();                   // also fences prev epilogue smf reads
    const int tile = __builtin_amdgcn_readfirstlane(*slot);
    if (tile >= NTILES) break;

    const int s0 = (tile & 63) * 64;
    const int c0 = ((tile >> 6) & 3) * 128;
    const int b  = tile >> 8;
    const int qlen = Qlen[b];

    if (s0 >= qlen) {                  // fully masked tile: zeros (64 x 128)
      const f32x4 z4 = {0.f, 0.f, 0.f, 0.f};
#pragma unroll
      for (int it = 0; it < 4; ++it) {
        const int f4  = it * 512 + t;
        const int row = f4 >> 5;
        const int col = (f4 & 31) * 4;
        *(f32x4*)(out + (size_t)(b * SEQ + s0 + row) * NCOL + c0 + col) = z4;
      }
      continue;
    }
    const int vlen = Vlen[b];
    const int vl = (vlen == 0) ? 64 : vlen;  // uniform -1e12 shift cancels
    const int live = (((w & 3) * 16) < vl);  // wave has ANY unmasked col

    const size_t xg = (size_t)(b * SEQ + s0 + srow) * EMB + sk4;
    const size_t wb = (size_t)(c0 + w * 16 + l15) * EMB + quad * 8;
    const u16* Wqh_g = Wt                + wb;
    const u16* Wql_g = Wt + 1 * EMB*NCOL + wb;
    const u16* Wkh_g = Wt + 2 * EMB*NCOL + wb;
    const u16* Wkl_g = Wt + 3 * EMB*NCOL + wb;
    const u16* Wv_g  = Wt + 4 * EMB*NCOL + wb;

    f32x4 accQ[4], accK[4], accV[4];
#pragma unroll
    for (int rt = 0; rt < 4; ++rt) {
      const f32x4 z = {0.f, 0.f, 0.f, 0.f};
      accQ[rt] = z; accK[rt] = z; accV[rt] = z;
    }

    f32x4 rq, rk, rv;   // single in-flight staging slot

#define LOADX(TT) do { \
      rq = *(const f32x4*)(Xq + xg + (TT) * 32); \
      rk = *(const f32x4*)(Xk + xg + (TT) * 32); \
      rv = *(const f32x4*)(Xv + xg + (TT) * 32); \
    } while (0)

#define STAGE(BOFS) do { \
      f16* p_ = smem + (BOFS); \
      f16x4 qh_, ql_, kh_, kl_, vh_; \
      _Pragma("unroll") \
      for (int j = 0; j < 4; ++j) { \
        const float xq_ = rq[j]; const f16 qhh_ = (f16)xq_; \
        qh_[j] = qhh_; ql_[j] = (f16)(xq_ - (float)qhh_); \
        const float xk_ = rk[j]; const f16 khh_ = (f16)xk_; \
        kh_[j] = khh_; kl_[j] = (f16)(xk_ - (float)khh_); \
        vh_[j] = (f16)rv[j]; \
      } \
      *(f16x4*)(p_ + 0 * PLANE + swo) = qh_; \
      *(f16x4*)(p_ + 1 * PLANE + swo) = ql_; \
      *(f16x4*)(p_ + 2 * PLANE + swo) = kh_; \
      *(f16x4*)(p_ + 3 * PLANE + swo) = kl_; \
      *(f16x4*)(p_ + 4 * PLANE + swo) = vh_; \
    } while (0)

#define COMPUTE(BOFS, KK) do { \
      const f16* p_ = smem + (BOFS); \
      const f16x8 bqh_ = *(const f16x8*)(Wqh_g + (KK)); \
      const f16x8 bql_ = *(const f16x8*)(Wql_g + (KK)); \
      const f16x8 bkh_ = *(const f16x8*)(Wkh_g + (KK)); \
      const f16x8 bkl_ = *(const f16x8*)(Wkl_g + (KK)); \
      const f16x8 bv_  = *(const f16x8*)(Wv_g  + (KK)); \
      __builtin_amdgcn_s_setprio(1); \
      _Pragma("unroll") \
      for (int rt = 0; rt < 4; ++rt) { \
        const int ao_ = ao + rt * 512; \
        const f16x8 ah_ = *(const f16x8*)(p_ + 0 * PLANE + ao_); \
        const f16x8 al_ = *(const f16x8*)(p_ + 1 * PLANE + ao_); \
        accQ[rt] = __builtin_amdgcn_mfma_f32_16x16x32_f16(ah_, bqh_, accQ[rt], 0, 0, 0); \
        accQ[rt] = __builtin_amdgcn_mfma_f32_16x16x32_f16(ah_, bql_, accQ[rt], 0, 0, 0); \
        accQ[rt] = __builtin_amdgcn_mfma_f32_16x16x32_f16(al_, bqh_, accQ[rt], 0, 0, 0); \
      } \
      _Pragma("unroll") \
      for (int rt = 0; rt < 4; ++rt) { \
        const int ao_ = ao + rt * 512; \
        const f16x8 ah_ = *(const f16x8*)(p_ + 2 * PLANE + ao_); \
        const f16x8 al_ = *(const f16x8*)(p_ + 3 * PLANE + ao_); \
        accK[rt] = __builtin_amdgcn_mfma_f32_16x16x32_f16(ah_, bkh_, accK[rt], 0, 0, 0); \
        accK[rt] = __builtin_amdgcn_mfma_f32_16x16x32_f16(ah_, bkl_, accK[rt], 0, 0, 0); \
        accK[rt] = __builtin_amdgcn_mfma_f32_16x16x32_f16(al_, bkh_, accK[rt], 0, 0, 0); \
      } \
      _Pragma("unroll") \
      for (int rt = 0; rt < 4; ++rt) { \
        const f16x8 av_ = *(const f16x8*)(p_ + 4 * PLANE + ao + rt * 512); \
        accV[rt] = __builtin_amdgcn_mfma_f32_16x16x32_f16(av_, bv_, accV[rt], 0, 0, 0); \
      } \
      __builtin_amdgcn_s_setprio(0); \
    } while (0)

    // Prologue: stage data 0 into buf0.
    LOADX(0);
    STAGE(0);
    __syncthreads();

    // 16 K-tiles of 32; one barrier per step; unroll x2 for buffer toggle.
    // V_len-dead waves skip COMPUTE entirely (wave-uniform branch) but keep
    // staging + barrier duties.
#pragma unroll 1
    for (int tt = 0; tt < 16; tt += 2) {
      LOADX(tt + 1);
      if (live) { COMPUTE(0, tt * 32); }
      STAGE(BUFSZ);
      __syncthreads();
      if (tt < 14) LOADX(tt + 2);
      if (live) { COMPUTE(BUFSZ, (tt + 1) * 32); }
      if (tt < 14) STAGE(0);
      __syncthreads();
    }

#undef LOADX
#undef STAGE
#undef COMPUTE

    // -----------------------------------------------------------------------
    // Epilogue. Wave covers cols [w*16, w*16+16); head = (c0 + w*16)/64;
    // softmax over d=64 combines the head's 4 waves via LDS (max, sum).
    // Dead waves publish (-inf, 0) and write zeros.
    float* smf = (float*)smem;    // [8 waves][64 rows][2] = 4 KB (buf0)
    float eA[4][4];               // exp(a - m_local), [rt][r]

    if (live) {
#pragma unroll
      for (int rt = 0; rt < 4; ++rt) {
#pragma unroll
        for (int r = 0; r < 4; ++r) {
          const float a = accQ[rt][r] * accK[rt][r] * scale;
          const bool msk = ((w & 3) * 16 + l15) < vl;
          float mx = msk ? a : -3.0e38f;
#pragma unroll
          for (int off = 1; off < 16; off <<= 1) mx = fmaxf(mx, __shfl_xor(mx, off));
          const float e = msk ? __expf(a - mx) : 0.0f;
          eA[rt][r] = e;
          float sum = e;
#pragma unroll
          for (int off = 1; off < 16; off <<= 1) sum += __shfl_xor(sum, off);
          const int row = rt * 16 + quad * 4 + r;
          if (l15 == 0) {
            smf[(w * 64 + row) * 2 + 0] = mx;
            smf[(w * 64 + row) * 2 + 1] = sum;
          }
        }
      }
    } else {
      if (l15 == 0) {
#pragma unroll
        for (int rt = 0; rt < 4; ++rt)
#pragma unroll
          for (int r = 0; r < 4; ++r) {
            const int row = rt * 16 + quad * 4 + r;
            smf[(w * 64 + row) * 2 + 0] = -3.0e38f;
            smf[(w * 64 + row) * 2 + 1] = 0.0f;
          }
      }
    }
    __syncthreads();

    if (live) {
      const int wbase = w & 4;    // first wave of this head's 4-wave group
#pragma unroll
      for (int rt = 0; rt < 4; ++rt) {
#pragma unroll
        for (int r = 0; r < 4; ++r) {
          const int row = rt * 16 + quad * 4 + r;
          const int s   = s0 + row;
          float pm[4], ps[4];
          float M = -3.0e38f;
#pragma unroll
          for (int j = 0; j < 4; ++j) {
            pm[j] = smf[((wbase + j) * 64 + row) * 2 + 0];
            ps[j] = smf[((wbase + j) * 64 + row) * 2 + 1];
            M = fmaxf(M, pm[j]);
          }
          float S = 0.f;
#pragma unroll
          for (int j = 0; j < 4; ++j) S += ps[j] * __expf(pm[j] - M);
          const float qm = (s < qlen) ? 1.0f : 0.0f;
          const float f  = __expf(pm[w & 3] - M) * qm / S;
          const size_t ob = (size_t)(b * SEQ + s) * NCOL + c0 + w * 16 + l15;
          out[ob] = eA[rt][r] * f * accV[rt][r];
        }
      }
    } else {
#pragma unroll
      for (int rt = 0; rt < 4; ++rt) {
#pragma unroll
        for (int r = 0; r < 4; ++r) {
          const int row = rt * 16 + quad * 4 + r;
          const int s   = s0 + row;
          const size_t ob = (size_t)(b * SEQ + s) * NCOL + c0 + w * 16 + l15;
          out[ob] = 0.0f;
        }
      }
    }
    // loop back: top-of-loop barrier protects smf before next tile's STAGE
  }
}

// ---------------------------------------------------------------------------
extern "C" void kernel_launch(void* const* d_in, const int* in_sizes, int n_in,
                              void* d_out, int out_size, void* d_ws, size_t ws_size,
                              hipStream_t stream) {
  const float* Xq   = (const float*)d_in[0];
  const float* Xk   = (const float*)d_in[1];
  const float* Xv   = (const float*)d_in[2];
  const int*   Qlen = (const int*)d_in[3];
  const int*   Vlen = (const int*)d_in[4];
  const float* Wq   = (const float*)d_in[5];
  const float* Wk   = (const float*)d_in[6];
  const float* Wv   = (const float*)d_in[7];
  u16*   Wt  = (u16*)d_ws;              // 5 * 512*512 * 2B = 2.62 MB
  float* out = (float*)d_out;

  const size_t wt_bytes = (size_t)5 * EMB * NCOL * sizeof(u16);
  u32* cnt = (u32*)((char*)d_ws + wt_bytes);
  const int dyn = (ws_size >= wt_bytes + sizeof(u32)) ? 1 : 0;

  dim3 pg(8, 8, 5), pb(64, 4, 1);
  prep_w<<<pg, pb, 0, stream>>>(Wq, Wk, Wv, Wt);
  if (dyn) reset_cnt<<<1, 64, 0, stream>>>(cnt);

  dim3 g(dyn ? 1024 : NTILES, 1, 1), blk(512, 1, 1);
  fused_attn<<<g, blk, 0, stream>>>(Xq, Xk, Xv, Qlen, Vlen, Wt, out, cnt, dyn);
}